// Round 7
// baseline (367.451 us; speedup 1.0000x reference)
//
#include <hip/hip_runtime.h>
#include <math.h>

// Problem constants: B=64, N=64, D=6, L=32, T=2048
#define TB 2048
#define LL 32
#define NP 64
#define DD 6
#define BB 64
#define NLANES 8        // lanes per DP problem
#define ROWS 4          // pattern rows per lane (L = 8*4 = 32)
#define CW 16           // columns per macro-step (tile width)
#define MSTEPS (TB/CW)  // 128
#define XSTRIDE 20      // floats per 16-float x block (80 B: bank-swizzled)

// Recurrence:
//   D[0, j] = c[0, j]
//   D[i, j] = c[i, j] + w * min(D[i-1, j], D[i, j-1], D[i-1, j-1])
//   out[b,n,d,j] = sqrt(D[L-1, j])
//
// R0-R5 lesson: ANY LDS op on the wave's serial dependency path costs
// ~400-500 cyc at 12 waves/CU (bpermute, batched bpermute, and conflict-free
// read/write tiles all land at ~5800 cyc/mstep; conflicts 6.3e6 -> 49k with
// zero time change => latency, not LDS bandwidth). R6: the boundary pass is a
// shift-by-1 within 8-lane groups == DPP row_shr:1 — cross-lane ON THE VALU
// PIPE, zero LDS, zero exposed latency. Lanes 8g get wrong-group data but are
// k0 (up/diag feed only the discarded m0 path). INF-init r3/carries keeps
// ramp-in exact: fma(w, INF, c) = INF self-propagates (verified R1-R5).
// x-tile LDS reads remain, but have NO loop-carried hazard (xs written once;
// no memory fence) + explicit register double-buffer -> latency pipelines.

__device__ __forceinline__ float dpp_shr1(float v) {
    const int i = __float_as_int(v);
    // row_shr:1 (0x111), all rows/banks, bound_ctrl=false (keep old = own val)
    const int r = __builtin_amdgcn_update_dpp(i, i, 0x111, 0xF, 0xF, false);
    return __int_as_float(r);
}

__global__ __launch_bounds__(256) void dtw_kernel(
    const float* __restrict__ x,      // (B, D, T)
    const float* __restrict__ patts,  // (N, L)
    const float* __restrict__ wptr,   // scalar
    float* __restrict__ out)          // (B, N, D, T)
{
    __shared__ float xs[MSTEPS * XSTRIDE];    // 10240 B

    const int bid  = blockIdx.x;      // B*D*2 blocks
    const int half = bid & 1;         // which 32 of the 64 patterns
    const int bd   = bid >> 1;        // b*D + d
    const int tid  = threadIdx.x;

    const float INF = __builtin_inff();

    // Stage x[b,d,:] into xs, 16 floats per block at 20-float stride
    // (start bank 20q mod 32 covers all 32 banks across 8 consecutive tiles).
    const float4* xrow = (const float4*)(x + (size_t)bd * TB);
    #pragma unroll
    for (int i = 0; i < 2; ++i) {
        const int idx = tid + i * 256;          // float4 index 0..511
        const int qb = idx >> 2, sub = idx & 3;
        *(float4*)(xs + qb * XSTRIDE + sub * 4) = xrow[idx];
    }
    __syncthreads();

    const int g = tid >> 3;           // group 0..31 (one pattern each)
    const int k = tid & 7;            // lane within group
    const int n = half * 32 + g;

    const float w = wptr[0];
    const float4 pv = *(const float4*)(patts + n * LL + k * ROWS);
    const float p0 = pv.x, p1 = pv.y, p2 = pv.z, p3 = pv.w;

    const int b = bd / DD, d = bd - (bd / DD) * DD;
    float* __restrict__ orow = out + (((size_t)b * NP + n) * DD + d) * TB;

    const bool k0 = (k == 0), k7 = (k == NLANES - 1);

    float a0 = INF, a1 = INF, a2 = INF, a3 = INF;   // left-column carries
    float diagC = INF;                              // diag for tile col 0
    float r3[CW];                                   // own boundary row, last block
    #pragma unroll
    for (int c = 0; c < CW; ++c) r3[c] = INF;

    // Current x tile in registers (q = clamp(0 - k) = 0).
    float4 xA = *(const float4*)(xs + 0);
    float4 xB = *(const float4*)(xs + 4);
    float4 xC = *(const float4*)(xs + 8);
    float4 xD = *(const float4*)(xs + 12);

    for (int m = 0; m < MSTEPS + NLANES - 1; ++m) {
        const int q = m - k;
        const bool valid = ((unsigned)q < (unsigned)MSTEPS);

        // ---- boundary pass: 16 DPP row_shr:1 movs, pure VALU ----
        float recv[CW];
        #pragma unroll
        for (int c = 0; c < CW; ++c) recv[c] = dpp_shr1(r3[c]);

        // ---- prefetch next x tile (no loop-carried hazard; double-buffered)
        int qn = m + 1 - k;
        qn = qn < 0 ? 0 : (qn > MSTEPS - 1 ? MSTEPS - 1 : qn);
        const float* xbn = xs + qn * XSTRIDE;
        const float4 nA = *(const float4*)(xbn + 0);
        const float4 nB = *(const float4*)(xbn + 4);
        const float4 nC = *(const float4*)(xbn + 8);
        const float4 nD = *(const float4*)(xbn + 12);

        const float xv[CW] = {xA.x, xA.y, xA.z, xA.w,  xB.x, xB.y, xB.z, xB.w,
                              xC.x, xC.y, xC.z, xC.w,  xD.x, xD.y, xD.z, xD.w};

        // ---- compute phase: 64 cells, pure VALU ----
        float diag = diagC;
        #pragma unroll
        for (int c = 0; c < CW; ++c) {
            const float xvc = xv[c];
            float t0 = p0 - xvc, t1 = p1 - xvc, t2 = p2 - xvc, t3 = p3 - xvc;
            const float c0 = t0 * t0, c1 = t1 * t1, c2 = t2 * t2, c3 = t3 * t3;
            const float up = recv[c];
            const float l0 = a0, l1 = a1, l2 = a2, l3 = a3;

            const float m0 = fminf(fminf(l0, up), diag);   // v_min3
            const float v0 = k0 ? c0 : fmaf(w, m0, c0);    // row 0: free start
            const float m1 = fminf(fminf(l1, v0), l0);
            const float v1 = fmaf(w, m1, c1);
            const float m2 = fminf(fminf(l2, v1), l1);
            const float v2 = fmaf(w, m2, c2);
            const float m3 = fminf(fminf(l3, v2), l2);
            const float v3 = fmaf(w, m3, c3);

            a0 = v0; a1 = v1; a2 = v2; a3 = v3;
            diag = up;
            r3[c] = v3;
        }
        diagC = recv[CW - 1];   // diag seed for next block's col 0

        // Row L-1 output: 64 B contiguous per macro-step.
        if (k7 && valid) {
            float4* op = (float4*)(orow + q * CW);
            op[0] = make_float4(sqrtf(r3[0]),  sqrtf(r3[1]),  sqrtf(r3[2]),  sqrtf(r3[3]));
            op[1] = make_float4(sqrtf(r3[4]),  sqrtf(r3[5]),  sqrtf(r3[6]),  sqrtf(r3[7]));
            op[2] = make_float4(sqrtf(r3[8]),  sqrtf(r3[9]),  sqrtf(r3[10]), sqrtf(r3[11]));
            op[3] = make_float4(sqrtf(r3[12]), sqrtf(r3[13]), sqrtf(r3[14]), sqrtf(r3[15]));
        }

        xA = nA; xB = nB; xC = nC; xD = nD;
    }
}

extern "C" void kernel_launch(void* const* d_in, const int* in_sizes, int n_in,
                              void* d_out, int out_size, void* d_ws, size_t ws_size,
                              hipStream_t stream) {
    const float* x     = (const float*)d_in[0];
    const float* patts = (const float*)d_in[1];
    const float* wptr  = (const float*)d_in[2];
    float* out = (float*)d_out;

    dim3 grid(BB * DD * 2);   // 768 blocks: one (b,d) per pair of blocks
    dim3 block(256);          // 32 pattern-groups of 8 lanes
    dtw_kernel<<<grid, block, 0, stream>>>(x, patts, wptr, out);
}

// Round 8
// 364.762 us; speedup vs baseline: 1.0074x; 1.0074x over previous
//
#include <hip/hip_runtime.h>
#include <math.h>

// Problem constants: B=64, N=64, D=6, L=32, T=2048
#define TB 2048
#define LL 32
#define NP 64
#define DD 6
#define BB 64
#define CW 16           // columns per macro-step
#define MSTEPS (TB/CW)  // 128
#define XSTRIDE 20      // floats per 16-float x block (80 B, bank-covering)

// R0-R6 lesson: VALUBusy ~103-115 in EVERY round == the VALU issue pipe is
// saturated; we are instruction-count-bound, not latency/LDS-bound (DPP
// removal of all comm LDS made it slower, conflict elimination was a no-op).
// VGPR_Count 28-44 with three live 16-float arrays proves the allocator
// parked arrays in AGPRs and shuttles them via v_accvgpr_read/write — pure
// VALU bloat (~3.5x the semantic instruction count). R7: straight-line body,
// ZERO local arrays (named scalars y0..y15), DPP boundary pass fused per
// column, no xv[] copies, no double-buffer movs, square fused into the fma.
// Essential: 17 VALU/column + 1 DPP -> ~290 inst/mstep/wave -> ~110 us floor.
//
// DPP row_shr:1 passes y within 16-lane rows; lanes 0,8 of each row receive
// junk/own-old but are k0 lanes whose up/diag feed only the discarded m0
// path (verified exact in R6: absmax 0). INF init makes ramp-in exact:
// fma(w, INF, c) = INF self-propagates. Ramp-out garbage is finite and only
// consumed by lanes processing invalid blocks (no store).

__device__ __forceinline__ float dpp_shr1(float v) {
    const int i = __float_as_int(v);
    // row_shr:1, all rows/banks, bound_ctrl=false (lane0 of row keeps old)
    const int r = __builtin_amdgcn_update_dpp(i, i, 0x111, 0xF, 0xF, false);
    return __int_as_float(r);
}

// One DP column: cost c_i = (p_i - xv)^2; D_i = c_i + w*min(left_i, up_i, diag_i).
// up for row0 comes from DPP(Y) (lane k-1's bottom row, previous mstep);
// rows 1-3 take up/diag from the in-register neighbors.
#define STEP(XV, Y) {                                        \
    const float up = dpp_shr1(Y);                            \
    const float t0 = p0 - (XV);                              \
    const float t1 = p1 - (XV);                              \
    const float t2 = p2 - (XV);                              \
    const float t3 = p3 - (XV);                              \
    const float c0 = t0 * t0;                                \
    const float m0 = fminf(fminf(a0, up), diag);             \
    const float v0 = k0 ? c0 : fmaf(w, m0, c0);              \
    const float m1 = fminf(fminf(a1, v0), a0);               \
    const float v1 = fmaf(w, m1, t1 * t1);                   \
    const float m2 = fminf(fminf(a2, v1), a1);               \
    const float v2 = fmaf(w, m2, t2 * t2);                   \
    const float m3 = fminf(fminf(a3, v2), a2);               \
    const float v3 = fmaf(w, m3, t3 * t3);                   \
    a0 = v0; a1 = v1; a2 = v2; a3 = v3;                      \
    diag = up;                                               \
    Y = v3;                                                  \
}

__global__ __launch_bounds__(64, 3) void dtw_kernel(
    const float* __restrict__ x,      // (B, D, T)
    const float* __restrict__ patts,  // (N, L)
    const float* __restrict__ wptr,   // scalar
    float* __restrict__ out)          // (B, N, D, T)
{
    __shared__ float xs[MSTEPS * XSTRIDE];    // 10240 B

    const int bid = blockIdx.x;       // BB*DD*8 = 3072 single-wave blocks
    const int oct = bid & 7;          // which 8 of the 64 patterns
    const int bd  = bid >> 3;         // b*D + d
    const int tid = threadIdx.x;      // 0..63

    const float INF = __builtin_inff();

    // Stage x[b,d,:] into xs at 20-float tile stride (tiles q..q+7 start at
    // banks {0,20,8,28,16,4,24,12}*? -> each wave's 8 distinct b128 addrs
    // cover all 32 banks; 8-lane same-address broadcast within).
    const float4* xrow = (const float4*)(x + (size_t)bd * TB);
    #pragma unroll
    for (int i = 0; i < 8; ++i) {
        const int idx = tid + i * 64;             // float4 index 0..511
        *(float4*)(xs + (idx >> 2) * XSTRIDE + (idx & 3) * 4) = xrow[idx];
    }
    __syncthreads();

    const int g = tid >> 3;           // group 0..7 (one pattern each)
    const int k = tid & 7;            // lane within group (rows 4k..4k+3)
    const int n = oct * 8 + g;

    const float w = wptr[0];
    const float4 pv = *(const float4*)(patts + n * LL + k * 4);
    const float p0 = pv.x, p1 = pv.y, p2 = pv.z, p3 = pv.w;

    const int b = bd / DD, d = bd - (bd / DD) * DD;
    float* __restrict__ orow = out + (((size_t)b * NP + n) * DD + d) * TB;

    const bool k0 = (k == 0), k7 = (k == 7);

    float a0 = INF, a1 = INF, a2 = INF, a3 = INF;   // left-column carries
    float diag = INF;                               // diag carry
    float y0 = INF, y1 = INF, y2 = INF, y3 = INF,   // own bottom row, last block
          y4 = INF, y5 = INF, y6 = INF, y7 = INF,
          y8 = INF, y9 = INF, y10 = INF, y11 = INF,
          y12 = INF, y13 = INF, y14 = INF, y15 = INF;

    for (int m = 0; m < MSTEPS + 7; ++m) {
        const int q = m - k;
        const bool valid = ((unsigned)q < (unsigned)MSTEPS);
        const int qq = valid ? q : 0;
        const float* xb = xs + qq * XSTRIDE;

        const float4 xA = *(const float4*)(xb + 0);
        const float4 xB = *(const float4*)(xb + 4);
        const float4 xC = *(const float4*)(xb + 8);
        const float4 xD = *(const float4*)(xb + 12);

        STEP(xA.x, y0)  STEP(xA.y, y1)  STEP(xA.z, y2)  STEP(xA.w, y3)
        STEP(xB.x, y4)  STEP(xB.y, y5)  STEP(xB.z, y6)  STEP(xB.w, y7)
        STEP(xC.x, y8)  STEP(xC.y, y9)  STEP(xC.z, y10) STEP(xC.w, y11)
        STEP(xD.x, y12) STEP(xD.y, y13) STEP(xD.z, y14) STEP(xD.w, y15)

        // Row L-1 output: 64 B contiguous per macro-step (k7 lanes only).
        if (k7 && valid) {
            float4* op = (float4*)(orow + q * CW);
            op[0] = make_float4(sqrtf(y0),  sqrtf(y1),  sqrtf(y2),  sqrtf(y3));
            op[1] = make_float4(sqrtf(y4),  sqrtf(y5),  sqrtf(y6),  sqrtf(y7));
            op[2] = make_float4(sqrtf(y8),  sqrtf(y9),  sqrtf(y10), sqrtf(y11));
            op[3] = make_float4(sqrtf(y12), sqrtf(y13), sqrtf(y14), sqrtf(y15));
        }
    }
}

extern "C" void kernel_launch(void* const* d_in, const int* in_sizes, int n_in,
                              void* d_out, int out_size, void* d_ws, size_t ws_size,
                              hipStream_t stream) {
    const float* x     = (const float*)d_in[0];
    const float* patts = (const float*)d_in[1];
    const float* wptr  = (const float*)d_in[2];
    float* out = (float*)d_out;

    dim3 grid(BB * DD * 8);   // 3072 single-wave blocks
    dim3 block(64);           // 8 pattern-groups of 8 lanes
    dtw_kernel<<<grid, block, 0, stream>>>(x, patts, wptr, out);
}

// Round 9
// 322.504 us; speedup vs baseline: 1.1394x; 1.1310x over previous
//
#include <hip/hip_runtime.h>
#include <math.h>

// Problem constants: B=64, N=64, D=6, L=32, T=2048
#define TB 2048
#define LL 32
#define NP 64
#define DD 6
#define BB 64
#define CW 16           // columns per macro-step
#define MSTEPS (TB/CW)  // 128
#define NL 16           // lanes per DP problem (was 8)
#define RW 2            // rows per lane (L = 16*2 = 32)
#define XSTRIDE 20      // floats per 16-float x block (80 B, bank-covering)

// R0-R7 ladder: comm mechanism changes (bpermute/batched/LDS-tiles/DPP) all
// land 300-400 us. Invariant: 3 waves/SIMD (grid pinned by the 8-lane
// decomposition) with a ~15-cyc dependent chain per column and ~3 cyc/instr
// real fp32 throughput -> each wave issues every ~7 cyc; TLP-starved.
// R8: 16 lanes/problem x 2 rows/lane -> 6144 waves = 6/SIMD (2x TLP) for
// only ~+20% instructions/cell. DPP row_shr:1 works entirely within 16-lane
// rows == the new group size. sqrtf -> __builtin_amdgcn_sqrtf (1 v_sqrt_f32
// instead of the guarded libm expansion; ~1e-5 abs err vs 0.41 threshold).
//
// Per-column recurrence for lane k (rows 2k, 2k+1):
//   up   = DPP(Y)  = lane k-1's row(2k-1) value, this column
//   diag = previous column's up
//   v0 = k0 ? c0 : c0 + w*min(a0, up, diag)
//   v1 = c1 + w*min(a1, v0, a0)
// INF init keeps ramp-in exact (fma(w,INF,c)=INF self-propagates; verified
// absmax 0.0 across R1-R7). Lane 0 of each row keeps its own old Y under
// bound_ctrl=false; that junk feeds only the k0-discarded m0 path.

__device__ __forceinline__ float dpp_shr1(float v) {
    const int i = __float_as_int(v);
    // row_shr:1, all rows/banks, bound_ctrl=false (lane0 of row keeps old)
    const int r = __builtin_amdgcn_update_dpp(i, i, 0x111, 0xF, 0xF, false);
    return __int_as_float(r);
}

#define STEP2(XV, Y) {                                       \
    const float up = dpp_shr1(Y);                            \
    const float t0 = p0 - (XV);                              \
    const float t1 = p1 - (XV);                              \
    const float c0 = t0 * t0;                                \
    const float m0 = fminf(fminf(a0, up), diag);             \
    const float f0 = fmaf(w, m0, c0);                        \
    const float v0 = k0 ? c0 : f0;                           \
    const float m1 = fminf(fminf(a1, v0), a0);               \
    const float v1 = fmaf(w, m1, t1 * t1);                   \
    a0 = v0; a1 = v1; diag = up;                             \
    Y = v1;                                                  \
}

__global__ __launch_bounds__(256) void dtw_kernel(
    const float* __restrict__ x,      // (B, D, T)
    const float* __restrict__ patts,  // (N, L)
    const float* __restrict__ wptr,   // scalar
    float* __restrict__ out)          // (B, N, D, T)
{
    __shared__ float xs[MSTEPS * XSTRIDE];    // 10240 B

    const int bid  = blockIdx.x;      // B*D*4 = 1536 blocks
    const int quad = bid & 3;         // which 16 of the 64 patterns
    const int bd   = bid >> 2;        // b*D + d
    const int tid  = threadIdx.x;     // 0..255

    const float INF = __builtin_inff();

    // Stage x[b,d,:] into xs at 20-float tile stride.
    const float4* xrow = (const float4*)(x + (size_t)bd * TB);
    #pragma unroll
    for (int i = 0; i < 2; ++i) {
        const int idx = tid + i * 256;            // float4 index 0..511
        *(float4*)(xs + (idx >> 2) * XSTRIDE + (idx & 3) * 4) = xrow[idx];
    }
    __syncthreads();

    const int g = tid >> 4;           // group 0..15 (one pattern each)
    const int k = tid & 15;           // lane within group (rows 2k, 2k+1)
    const int n = quad * 16 + g;

    const float w = wptr[0];
    const float2 pv = *(const float2*)(patts + n * LL + k * RW);
    const float p0 = pv.x, p1 = pv.y;

    const int b = bd / DD, d = bd - (bd / DD) * DD;
    float* __restrict__ orow = out + (((size_t)b * NP + n) * DD + d) * TB;

    const bool k0 = (k == 0), kl = (k == NL - 1);

    float a0 = INF, a1 = INF;         // left-column carries (2 rows)
    float diag = INF;                 // diag carry
    float y0 = INF, y1 = INF, y2 = INF, y3 = INF,   // own bottom row, last blk
          y4 = INF, y5 = INF, y6 = INF, y7 = INF,
          y8 = INF, y9 = INF, y10 = INF, y11 = INF,
          y12 = INF, y13 = INF, y14 = INF, y15 = INF;

    for (int m = 0; m < MSTEPS + NL - 1; ++m) {
        const int q = m - k;
        const bool valid = ((unsigned)q < (unsigned)MSTEPS);
        const int qq = valid ? q : 0;
        const float* xb = xs + qq * XSTRIDE;

        const float4 xA = *(const float4*)(xb + 0);
        const float4 xB = *(const float4*)(xb + 4);
        const float4 xC = *(const float4*)(xb + 8);
        const float4 xD = *(const float4*)(xb + 12);

        STEP2(xA.x, y0)  STEP2(xA.y, y1)  STEP2(xA.z, y2)  STEP2(xA.w, y3)
        STEP2(xB.x, y4)  STEP2(xB.y, y5)  STEP2(xB.z, y6)  STEP2(xB.w, y7)
        STEP2(xC.x, y8)  STEP2(xC.y, y9)  STEP2(xC.z, y10) STEP2(xC.w, y11)
        STEP2(xD.x, y12) STEP2(xD.y, y13) STEP2(xD.z, y14) STEP2(xD.w, y15)

        // Row L-1 output: lane 15 of each group, 64 B contiguous per mstep.
        if (kl && valid) {
            float4* op = (float4*)(orow + q * CW);
            op[0] = make_float4(__builtin_amdgcn_sqrtf(y0),
                                __builtin_amdgcn_sqrtf(y1),
                                __builtin_amdgcn_sqrtf(y2),
                                __builtin_amdgcn_sqrtf(y3));
            op[1] = make_float4(__builtin_amdgcn_sqrtf(y4),
                                __builtin_amdgcn_sqrtf(y5),
                                __builtin_amdgcn_sqrtf(y6),
                                __builtin_amdgcn_sqrtf(y7));
            op[2] = make_float4(__builtin_amdgcn_sqrtf(y8),
                                __builtin_amdgcn_sqrtf(y9),
                                __builtin_amdgcn_sqrtf(y10),
                                __builtin_amdgcn_sqrtf(y11));
            op[3] = make_float4(__builtin_amdgcn_sqrtf(y12),
                                __builtin_amdgcn_sqrtf(y13),
                                __builtin_amdgcn_sqrtf(y14),
                                __builtin_amdgcn_sqrtf(y15));
        }
    }
}

extern "C" void kernel_launch(void* const* d_in, const int* in_sizes, int n_in,
                              void* d_out, int out_size, void* d_ws, size_t ws_size,
                              hipStream_t stream) {
    const float* x     = (const float*)d_in[0];
    const float* patts = (const float*)d_in[1];
    const float* wptr  = (const float*)d_in[2];
    float* out = (float*)d_out;

    dim3 grid(BB * DD * 4);   // 1536 blocks: (b,d) x 16-pattern quads
    dim3 block(256);          // 16 groups of 16 lanes; 4 waves/block
    dtw_kernel<<<grid, block, 0, stream>>>(x, patts, wptr, out);
}